// Round 5
// baseline (383.690 us; speedup 1.0000x reference)
//
#include <hip/hip_runtime.h>
#include <stdint.h>

#define B_DIM 4096
#define IN_SZ 1024
#define HID   2048
#define D_DIM 3072   // K = IN_SZ + HID
#define BM 256       // batch rows per block
#define BN 64        // h-columns per block (x4 gates = 256 logical cols)
#define BK 64        // K-step (bf16 elems)
#define NT (D_DIM / BK)   // 48

typedef float  f32x4  __attribute__((ext_vector_type(4)));
typedef short  short8 __attribute__((ext_vector_type(8)));

__device__ __forceinline__ unsigned short f2bf(float f) {
    union { float f; unsigned u; } v; v.f = f;
    unsigned u = v.u + 0x7fffu + ((v.u >> 16) & 1u);   // RNE
    return (unsigned short)(u >> 16);
}

__device__ __forceinline__ void async_load16(const void* g, void* l) {
    __builtin_amdgcn_global_load_lds(
        (const __attribute__((address_space(1))) unsigned int*)g,
        (__attribute__((address_space(3))) unsigned int*)l,
        16, 0, 0);
}

__device__ __forceinline__ float sigm(float x) {
    return 1.0f / (1.0f + __expf(-x));
}
__device__ __forceinline__ float tanh_f(float x) {
    return 1.0f - 2.0f / (__expf(2.0f * x) + 1.0f);
}

// ---- single prepass: concat(x,h)->bf16 [B][D]  and  concat(W_i..W_o)->bf16 [4H][D] ----
__global__ __launch_bounds__(256)
void convert_all(const float* __restrict__ x, const float* __restrict__ h,
                 const float* __restrict__ W0, const float* __restrict__ W1,
                 const float* __restrict__ W2, const float* __restrict__ W3,
                 unsigned short* __restrict__ Abf, unsigned short* __restrict__ Wbf) {
    const int NA = B_DIM * D_DIM / 8;        // 1,572,864
    const int NW = 4 * HID * D_DIM / 8;      // 3,145,728
    int idx = blockIdx.x * blockDim.x + threadIdx.x;
    const float* src;
    unsigned short* dst;
    if (idx < NA) {
        const int C8 = D_DIM / 8;            // 384
        int b = idx / C8, c8 = idx - b * C8;
        src = (c8 < IN_SZ / 8) ? x + (size_t)b * IN_SZ + c8 * 8
                               : h + (size_t)b * HID + (c8 - IN_SZ / 8) * 8;
        dst = Abf + (size_t)idx * 8;
    } else {
        int wi = idx - NA;
        if (wi >= NW) return;
        const int PG = HID * D_DIM / 8;      // 786,432 per gate
        int g = wi / PG, r = wi - g * PG;
        const float* W = (g == 0) ? W0 : (g == 1) ? W1 : (g == 2) ? W2 : W3;
        src = W + (size_t)r * 8;
        dst = Wbf + (size_t)wi * 8;
    }
    float4 v0 = ((const float4*)src)[0];
    float4 v1 = ((const float4*)src)[1];
    short8 o;
    o[0] = (short)f2bf(v0.x); o[1] = (short)f2bf(v0.y);
    o[2] = (short)f2bf(v0.z); o[3] = (short)f2bf(v0.w);
    o[4] = (short)f2bf(v1.x); o[5] = (short)f2bf(v1.y);
    o[6] = (short)f2bf(v1.z); o[7] = (short)f2bf(v1.w);
    *(short8*)dst = o;
}

// ---------- MFMA cluster: 16 MFMAs = m-frags [IB..IB+4) x all 4 n-frags, one k-slice
template <int IB>
__device__ __forceinline__ void mfma16(f32x4 (&acc)[8][4], const short8 (&a)[4],
                                       const short8 (&b)[4]) {
#pragma unroll
    for (int i = 0; i < 4; ++i)
#pragma unroll
        for (int j = 0; j < 4; ++j)
            acc[IB + i][j] = __builtin_amdgcn_mfma_f32_16x16x32_bf16(
                a[i], b[j], acc[IB + i][j], 0, 0, 0);
}

// One K-tile = 4 phases, m201-style schedule:
//   ph1: read F1{a0s0,bs0} (own frags, one serial batch/tile) + F2{a1s0};
//        stage A(kt+1)->nxt AFTER reads; MFMA1 (counted lgkm leaves F2 in flight)
//   ph2: read F3{a0s1,bs1}; stage B(kt+1)->nxt; MFMA2
//   ph3: read F4{a1s1}; MFMA3
//   ph4: MFMA4 (its lgkm wait retires ALL cur-reads -> cur safely overwritable)
//        vmcnt(0) (stages issued 3-4 phases ago) + single tile-end barrier
// ds_reads issued BEFORE stages each phase (reads never queue behind pending
// gload_lds LDS-writes); gload_lds counts in vmcnt, not lgkmcnt, so the
// compiler's per-phase counted lgkm waits stay exact.
// MODE: 1 = steady (stage kt+1), 0 = last tile (no stage, no barrier).
template <int MODE>
__device__ __forceinline__ void tile_body(
    f32x4 (&acc)[8][4], const char* cur, char* nxt,
    const unsigned short* srcA0, const unsigned short* const* srcB,
    int koff, int chunk, int aBase, int bBase, int sw0, int sw1) {
    const char* curA = cur;
    const char* curB = cur + 32768;
    short8 a0s0[4], a1s0[4], a0s1[4], a1s1[4], bs0[4], bs1[4];

    // ================= phase 1: MFMA m0-3 x s0 =================
#pragma unroll
    for (int i = 0; i < 4; ++i)
        a0s0[i] = *(const short8*)(curA + aBase + i * 2048 + sw0);
#pragma unroll
    for (int j = 0; j < 4; ++j)
        bs0[j] = *(const short8*)(curB + bBase + j * 2048 + sw0);
#pragma unroll
    for (int i = 0; i < 4; ++i)
        a1s0[i] = *(const short8*)(curA + aBase + (4 + i) * 2048 + sw0);
    if (MODE) {
#pragma unroll
        for (int i = 0; i < 4; ++i)
            async_load16(srcA0 + i * 8 * D_DIM + koff, nxt + chunk + i * 1024);
    }
    __builtin_amdgcn_sched_barrier(0);
    __builtin_amdgcn_s_setprio(1);
    mfma16<0>(acc, a0s0, bs0);
    __builtin_amdgcn_s_setprio(0);

    // ================= phase 2: MFMA m4-7 x s0 =================
#pragma unroll
    for (int i = 0; i < 4; ++i)
        a0s1[i] = *(const short8*)(curA + aBase + i * 2048 + sw1);
#pragma unroll
    for (int j = 0; j < 4; ++j)
        bs1[j] = *(const short8*)(curB + bBase + j * 2048 + sw1);
    if (MODE) {
#pragma unroll
        for (int i = 0; i < 4; ++i)
            async_load16(srcB[i] + koff, nxt + 32768 + chunk + i * 1024);
    }
    __builtin_amdgcn_sched_barrier(0);
    __builtin_amdgcn_s_setprio(1);
    mfma16<4>(acc, a1s0, bs0);
    __builtin_amdgcn_s_setprio(0);

    // ================= phase 3: MFMA m0-3 x s1 =================
#pragma unroll
    for (int i = 0; i < 4; ++i)
        a1s1[i] = *(const short8*)(curA + aBase + (4 + i) * 2048 + sw1);
    __builtin_amdgcn_sched_barrier(0);
    __builtin_amdgcn_s_setprio(1);
    mfma16<0>(acc, a0s1, bs1);
    __builtin_amdgcn_s_setprio(0);

    // ================= phase 4: MFMA m4-7 x s1 =================
    __builtin_amdgcn_sched_barrier(0);
    __builtin_amdgcn_s_setprio(1);
    mfma16<4>(acc, a1s1, bs1);      // lgkm wait here retires all cur-reads
    __builtin_amdgcn_s_setprio(0);
    if (MODE) {
        asm volatile("s_waitcnt vmcnt(0)" ::: "memory");   // stages landed (3-4 ph slack)
        __builtin_amdgcn_s_barrier();                      // single barrier per tile
        asm volatile("" ::: "memory");
    }
}

// ---- fused gate-GEMM + LSTM epilogue, 256x(64h x 4gates) tile, BK=64, 8 waves ----
// Column mapping: col = h_hi*64 + gate*16 + h_lo -> all 4 gates of an (m,h) share a lane.
// LDS: 2 x (A 32K | B 32K) = 128 KiB, [row][64] bf16 rows (128 B) with slot^=row&7 XOR
// swizzle on BOTH the pre-swizzled global staging source and the ds_read offset.
__global__ __launch_bounds__(512, 2)
void lstm_gemm(const unsigned short* __restrict__ Abf,   // [B][D] bf16
               const unsigned short* __restrict__ Wbf,   // [4H][D] bf16
               const float* __restrict__ b_i, const float* __restrict__ b_f,
               const float* __restrict__ b_c, const float* __restrict__ b_o,
               const float* __restrict__ c_prev,
               float* __restrict__ h_out, float* __restrict__ c_out) {
    extern __shared__ char sm[];   // 131072 B

    const int tid  = threadIdx.x;
    const int lane = tid & 63;
    const int wave = tid >> 6;          // 0..7
    const int wm   = wave >> 2;         // 0..1
    const int wn   = wave & 3;          // 0..3
    const int l16  = lane & 15;
    const int quad = lane >> 4;
    const int r7   = l16 & 7;

    const int m0 = blockIdx.x * BM;
    const int h0 = blockIdx.y * BN;

    // staging: instruction (wave,i) covers tile rows (wave*4+i)*8 .. +8 (128 B each)
    const int g8 = lane >> 3;           // row within octet
    const int sl = (lane & 7) ^ g8;     // pre-swizzled source slot (involution)
    const unsigned short* srcA0 = Abf + (size_t)(m0 + wave * 32 + g8) * D_DIM + sl * 8;
    const unsigned short* srcB[4];
#pragma unroll
    for (int i = 0; i < 4; ++i) {
        const int rt = wave * 32 + i * 8 + g8;         // B tile row 0..255
        // B tile row -> W global row: gate=(rt>>4)&3, h = h0 + (rt>>6)*16 + (rt&15)
        const int grow = ((rt >> 4) & 3) * HID + h0 + (rt >> 6) * 16 + (rt & 15);
        srcB[i] = Wbf + (size_t)grow * D_DIM + sl * 8;
    }
    const int chunk = wave * 4096;      // per-wave stage region (+i*1024)

    // ds_read offsets: addr = row*128 + ((s*4+quad)^(row&7))*16, row&7 == l16&7
    const int aBase = (wm * 128 + l16) * 128;
    const int bBase = (wn * 64  + l16) * 128;
    const int sw0 = ((0 * 4 + quad) ^ r7) * 16;
    const int sw1 = ((1 * 4 + quad) ^ r7) * 16;

    f32x4 acc[8][4] = {};

    // ---- prologue: stage tile 0 -> buf0 ----
#pragma unroll
    for (int i = 0; i < 4; ++i) {
        async_load16(srcB[i], sm + 32768 + chunk + i * 1024);
        async_load16(srcA0 + i * 8 * D_DIM, sm + chunk + i * 1024);
    }
    asm volatile("s_waitcnt vmcnt(0)" ::: "memory");
    __builtin_amdgcn_s_barrier();
    asm volatile("" ::: "memory");

    for (int kt = 0; kt < NT - 1; ++kt) {
        const char* cur = sm + (kt & 1) * 65536;
        char* nxt = (char*)sm + ((kt + 1) & 1) * 65536;
        tile_body<1>(acc, cur, nxt, srcA0, srcB,
                     (kt + 1) * BK, chunk, aBase, bBase, sw0, sw1);
    }
    tile_body<0>(acc, sm + ((NT - 1) & 1) * 65536, (char*)sm,
                 srcA0, srcB, 0, chunk, aBase, bBase, sw0, sw1);

    // ---- epilogue: C layout col = lane&15, row = quad*4 + reg ----
    const int h = h0 + wn * 16 + l16;
    const float biv = b_i[h], bfv = b_f[h], bcv = b_c[h], bov = b_o[h];
    const int mb = m0 + wm * 128 + quad * 4;
#pragma unroll
    for (int i = 0; i < 8; ++i) {
#pragma unroll
        for (int r = 0; r < 4; ++r) {
            const int m = mb + i * 16 + r;
            const size_t off = (size_t)m * HID + h;
            const float gi = acc[i][0][r] + biv;
            const float gf = acc[i][1][r] + bfv;
            const float gc = acc[i][2][r] + bcv;
            const float go = acc[i][3][r] + bov;
            const float it = sigm(gi), ft = sigm(gf);
            const float gt = tanh_f(gc), ot = sigm(go);
            const float c = ft * c_prev[off] + it * gt;
            h_out[off] = ot * tanh_f(c);
            c_out[off] = c;
        }
    }
}

extern "C" void kernel_launch(void* const* d_in, const int* in_sizes, int n_in,
                              void* d_out, int out_size, void* d_ws, size_t ws_size,
                              hipStream_t stream) {
    const float* x_t    = (const float*)d_in[0];
    const float* h_prev = (const float*)d_in[1];
    const float* c_prev = (const float*)d_in[2];
    const float* W_i = (const float*)d_in[3];
    const float* b_i = (const float*)d_in[4];
    const float* W_f = (const float*)d_in[5];
    const float* b_f = (const float*)d_in[6];
    const float* W_c = (const float*)d_in[7];
    const float* b_c = (const float*)d_in[8];
    const float* W_o = (const float*)d_in[9];
    const float* b_o = (const float*)d_in[10];
    float* out = (float*)d_out;

    unsigned short* Abf = (unsigned short*)d_ws;                       // 25,165,824 B
    unsigned short* Wbf = (unsigned short*)((char*)d_ws + (size_t)B_DIM * D_DIM * 2);
    // total ws use: 75,497,472 B

    static bool s_attr = false;
    if (!s_attr) {
        (void)hipFuncSetAttribute((const void*)lstm_gemm,
                                  hipFuncAttributeMaxDynamicSharedMemorySize, 131072);
        s_attr = true;
    }

    {
        const int n = (B_DIM * D_DIM + 4 * HID * D_DIM) / 8;   // 4,718,592
        convert_all<<<n / 256, 256, 0, stream>>>(x_t, h_prev, W_i, W_f, W_c, W_o,
                                                 Abf, Wbf);
    }
    dim3 grid(B_DIM / BM, HID / BN);   // 16 x 32
    lstm_gemm<<<grid, 512, 131072, stream>>>(Abf, Wbf, b_i, b_f, b_c, b_o, c_prev,
                                             out, out + (size_t)B_DIM * HID);
}